// Round 14
// baseline (436.607 us; speedup 1.0000x reference)
//
#include <hip/hip_runtime.h>
#include <hip/hip_bf16.h>

#define NTOK   49
#define DIM    384
#define KEY_DIM 32
#define HEADS  8
#define D_HEAD 128
#define SCALE  0.17677669529663687f   // 32^-0.5

typedef short short8 __attribute__((ext_vector_type(8)));
typedef short short4_t __attribute__((ext_vector_type(4)));
typedef float f32x4 __attribute__((ext_vector_type(4)));

__device__ __forceinline__ unsigned short f2bf(float x) {
    union { __hip_bfloat16 b; unsigned short u; } v;
    v.b = __float2bfloat16(x);            // native HW cvt (RNE)
    return v.u;
}

__device__ __forceinline__ f32x4 MFMA(short8 a, short8 b, f32x4 c) {
    return __builtin_amdgcn_mfma_f32_16x16x32_bf16(a, b, c, 0, 0, 0);
}

// Barrier that drains ONLY LDS ops (lgkmcnt), not in-flight global loads /
// NT stores (vmcnt). Valid when all cross-wave hazards are LDS-resident.
__device__ __forceinline__ void bar_lgkm() {
    asm volatile("s_waitcnt lgkmcnt(0)" ::: "memory");
    __builtin_amdgcn_sched_barrier(0);
    __builtin_amdgcn_s_barrier();
    __builtin_amdgcn_sched_barrier(0);
}

// ---------------- prologue: weight packing + bias expansion ----------------
__global__ void prologue(const float* __restrict__ qw, const float* __restrict__ qb,
                         const float* __restrict__ kw,
                         const float* __restrict__ vw, const float* __restrict__ pw,
                         const float* __restrict__ biases, const int* __restrict__ idxs,
                         int n_off,
                         unsigned short* __restrict__ qk_p,
                         unsigned short* __restrict__ vw_p,
                         unsigned short* __restrict__ pw_p,
                         float* __restrict__ qb_s,
                         float* __restrict__ ab_t) {
    int t = blockIdx.x * 256 + threadIdx.x;
    if (t < 24576) {                       // QK pack: N=512 (Q|K), K=384, KT=12
        int lane = t & 63, kt = (t >> 6) % 12, ntile = t / 768;
        int c = ntile * 16 + (lane & 15), kk = kt * 32 + (lane >> 4) * 8;
        const float* src = (c < 256) ? (qw + c * 384 + kk) : (kw + (c - 256) * 384 + kk);
        float sc = (c < 256) ? SCALE : 1.0f;
        short8 o;
#pragma unroll
        for (int j = 0; j < 8; ++j) o[j] = (short)f2bf(src[j] * sc);
        *(short8*)(qk_p + (size_t)t * 8) = o;
    } else if (t < 73728) {                // V pack: N=1024, K=384, KT=12
        int u = t - 24576;
        int lane = u & 63, kt = (u >> 6) % 12, ntile = u / 768;
        int c = ntile * 16 + (lane & 15), kk = kt * 32 + (lane >> 4) * 8;
        const float* src = vw + c * 384 + kk;
        short8 o;
#pragma unroll
        for (int j = 0; j < 8; ++j) o[j] = (short)f2bf(src[j]);
        *(short8*)(vw_p + (size_t)u * 8) = o;
    } else if (t < 122880) {               // proj pack: N=384, K=1024, KT=32
        int u = t - 73728;
        int lane = u & 63, kt = (u >> 6) % 32, ntile = u / 2048;
        int c = ntile * 16 + (lane & 15), kk = kt * 32 + (lane >> 4) * 8;
        const float* src = pw + c * 1024 + kk;
        short8 o;
#pragma unroll
        for (int j = 0; j < 8; ++j) o[j] = (short)f2bf(src[j]);
        *(short8*)(pw_p + (size_t)u * 8) = o;
    } else if (t < 123136) {               // scaled q bias
        int u = t - 122880;
        qb_s[u] = qb[u] * SCALE;
    } else if (t < 123136 + 32768) {       // ab_t[h][n][m] (n=query, m=key), zero-padded 64x64
        int u = t - 123136;
        int h = u >> 12, n = (u >> 6) & 63, m = u & 63;
        float v = 0.f;
        if (m < 49 && n < 49) v = biases[h * n_off + idxs[n * 49 + m]];
        ab_t[u] = v;
    }
}

// ================================================================
// Kernel A (R12 structure + P0 B-frag double-buffer): QKV proj +
// attention + PV -> O C-frag packed.
//   O_p ushort offset (((b*8+h)*32 + frag)*64 + ln)*4 + r  holds
//   O[b][n = mt*16 + (ln>>4)*4 + r][dglob = h*128 + dt*16 + (ln&15)],
//   frag = mt*8 + dt.
// 8 heads/block, grid 2048. LDS 74,144 B -> 2 blocks/CU, (512,4).
// ================================================================
__global__ __launch_bounds__(512, 4) void attn_qkv(
        const float* __restrict__ x,
        const unsigned short* __restrict__ qkw,
        const unsigned short* __restrict__ vw,
        const float* __restrict__ qb_s, const float* __restrict__ kb,
        const float* __restrict__ vb,
        const float* __restrict__ ab_t,
        unsigned short* __restrict__ O_p) {

    __shared__ __align__(16) unsigned short smem[37072];   // 74,144 B
    unsigned short* xs  = smem;                // [49][392]
    unsigned short* ps  = smem + 19208;        // [49][72]
    unsigned short* vsT = smem + 22736;        // [128][72]
    unsigned short* qs  = smem + 31952;        // [64][40]
    unsigned short* ks2 = smem + 34512;        // [64][40]

    const int tid  = threadIdx.x;
    const int lane = tid & 63;
    const int wid  = tid >> 6;
    const int l15  = lane & 15;
    const int lg   = lane >> 4;
    const int b    = blockIdx.x;

    const float* xb = x + (size_t)b * (NTOK * DIM);
#pragma unroll 2
    for (int i = tid; i < 4704; i += 512) {
        f32x4 v = __builtin_nontemporal_load(((const f32x4*)xb) + i);
        int f = i * 4;
        int row = f / DIM;
        int col = f - row * DIM;
        short4_t pk;
        pk[0] = (short)f2bf(v[0]); pk[1] = (short)f2bf(v[1]);
        pk[2] = (short)f2bf(v[2]); pk[3] = (short)f2bf(v[3]);
        *(short4_t*)&xs[row * 392 + col] = pk;
    }
    __syncthreads();   // full drain once (staging)

    const f32x4 zf = (f32x4)0.f;

    for (int h = 0; h < HEADS; ++h) {
        // ---- P0: Q,K,V projection (B-frags double-buffered across kt) ----
        {
            const int mh  = wid >> 2;
            const int nt0 = 3 * (wid & 3);
            const int rA0 = min(mh * 32 + l15, 48);
            const int rA1 = min(mh * 32 + 16 + l15, 48);
            f32x4 acc[3][2];
#pragma unroll
            for (int i = 0; i < 3; ++i) { acc[i][0] = zf; acc[i][1] = zf; }

            const short8* bptr[3];
#pragma unroll
            for (int i = 0; i < 3; ++i) {
                int nt = nt0 + i;
                const unsigned short* base; int ntile;
                if (nt < 2)      { base = qkw; ntile = 2 * h + nt; }
                else if (nt < 4) { base = qkw; ntile = 16 + 2 * h + (nt - 2); }
                else             { base = vw;  ntile = 8 * h + (nt - 4); }
                bptr[i] = (const short8*)(base + (size_t)ntile * 12 * 64 * 8);
            }
            short8 bfc[3], bfn[3];
#pragma unroll
            for (int i = 0; i < 3; ++i) bfc[i] = bptr[i][lane];   // kt = 0
            __builtin_amdgcn_s_setprio(1);
#pragma unroll
            for (int kt = 0; kt < 12; ++kt) {
                if (kt < 11) {
#pragma unroll
                    for (int i = 0; i < 3; ++i) bfn[i] = bptr[i][(kt + 1) * 64 + lane];
                }
                short8 a0 = *(const short8*)&xs[rA0 * 392 + kt * 32 + lg * 8];
                short8 a1 = *(const short8*)&xs[rA1 * 392 + kt * 32 + lg * 8];
#pragma unroll
                for (int i = 0; i < 3; ++i) {
                    acc[i][0] = MFMA(a0, bfc[i], acc[i][0]);
                    acc[i][1] = MFMA(a1, bfc[i], acc[i][1]);
                }
#pragma unroll
                for (int i = 0; i < 3; ++i) bfc[i] = bfn[i];
            }
            __builtin_amdgcn_s_setprio(0);
#pragma unroll
            for (int i = 0; i < 3; ++i) {
                int nt = nt0 + i;
                int c  = nt * 16 + l15;
                if (nt < 4) {
                    int cc = (nt < 2) ? c : c - 32;
                    float bias = (nt < 2) ? qb_s[h * 32 + cc] : kb[h * 32 + cc];
                    unsigned short* dst = (nt < 2) ? qs : ks2;
#pragma unroll
                    for (int j = 0; j < 2; ++j) {
                        int r0 = mh * 32 + j * 16 + lg * 4;
                        f32x4 v = acc[i][j];
#pragma unroll
                        for (int r = 0; r < 4; ++r)
                            dst[(r0 + r) * 40 + cc] = f2bf(v[r] + bias);
                    }
                } else {
                    int d = c - 64;
                    float bias = vb[h * 128 + d];
#pragma unroll
                    for (int j = 0; j < 2; ++j) {
                        int m0 = mh * 32 + j * 16 + lg * 4;
                        f32x4 v = acc[i][j];
                        short4_t pk;
#pragma unroll
                        for (int r = 0; r < 4; ++r) pk[r] = (short)f2bf(v[r] + bias);
                        *(short4_t*)&vsT[d * 72 + m0] = pk;
                    }
                }
            }
        }
        bar_lgkm();   // bar A: qs/ks/vsT ready (LDS only)

        // ---- P1: S^T = K@Q^T, softmax (waves 0-3) ----
        if (wid < 4) {
            const int I = wid;
            const int rq = min(I * 16 + l15, 48);
            short8 bq = *(const short8*)&qs[rq * 40 + lg * 8];
            f32x4 s[4];
#pragma unroll
            for (int J = 0; J < 4; ++J) {
                short8 ak = *(const short8*)&ks2[(J * 16 + l15) * 40 + lg * 8];
                s[J] = MFMA(ak, bq, zf);
            }
            const f32x4* abn = (const f32x4*)(ab_t + ((h * 64 + I * 16 + l15) * 64));
            float sv[16];
            float mx = -1e30f;
#pragma unroll
            for (int J = 0; J < 4; ++J) {
                f32x4 a4 = abn[J * 4 + lg];
#pragma unroll
                for (int r = 0; r < 4; ++r) {
                    int m = J * 16 + lg * 4 + r;
                    float val = s[J][r] + a4[r];
                    if (m >= 49) val = -1e30f;
                    sv[J * 4 + r] = val;
                    mx = fmaxf(mx, val);
                }
            }
            mx = fmaxf(mx, __shfl_xor(mx, 16));
            mx = fmaxf(mx, __shfl_xor(mx, 32));
            float sum = 0.f;
#pragma unroll
            for (int t = 0; t < 16; ++t) { float e = __expf(sv[t] - mx); sv[t] = e; sum += e; }
            sum += __shfl_xor(sum, 16);
            sum += __shfl_xor(sum, 32);
            float inv = 1.0f / sum;
            int n = I * 16 + l15;
            if (n < 49) {
#pragma unroll
                for (int J = 0; J < 4; ++J)
#pragma unroll
                    for (int r = 0; r < 4; ++r) {
                        int m = J * 16 + lg * 4 + r;
                        ps[n * 72 + m] = f2bf(sv[J * 4 + r] * inv);
                    }
            }
        }
        bar_lgkm();   // bar B: ps ready (LDS only)

        // ---- P2a: O_h = P @ V_h -> direct packed global store (C-frag) ----
        {
            const int np = wid >> 2;
            const int dp = wid & 3;
            const int rp0 = min(np * 32 + l15, 48);
            const int rp1 = min(np * 32 + 16 + l15, 48);
            f32x4 a00 = zf, a01 = zf, a10 = zf, a11 = zf;
            __builtin_amdgcn_s_setprio(1);
#pragma unroll
            for (int kk = 0; kk < 2; ++kk) {
                short8 a0 = *(const short8*)&ps[rp0 * 72 + kk * 32 + lg * 8];
                short8 a1 = *(const short8*)&ps[rp1 * 72 + kk * 32 + lg * 8];
                short8 b0 = *(const short8*)&vsT[(dp * 32 + l15) * 72 + kk * 32 + lg * 8];
                short8 b1 = *(const short8*)&vsT[(dp * 32 + 16 + l15) * 72 + kk * 32 + lg * 8];
                a00 = MFMA(a0, b0, a00); a01 = MFMA(a0, b1, a01);
                a10 = MFMA(a1, b0, a10); a11 = MFMA(a1, b1, a11);
            }
            __builtin_amdgcn_s_setprio(0);
            f32x4 accs[2][2] = {{a00, a01}, {a10, a11}};
            unsigned short* ob = O_p + (((size_t)b * 8 + h) * 32) * 256;
#pragma unroll
            for (int jn = 0; jn < 2; ++jn)
#pragma unroll
                for (int jd = 0; jd < 2; ++jd) {
                    int frag = (np * 2 + jn) * 8 + (dp * 2 + jd);
                    f32x4 v = accs[jn][jd];
                    short4_t pk;
#pragma unroll
                    for (int r = 0; r < 4; ++r) pk[r] = (short)f2bf(v[r]);
                    __builtin_nontemporal_store(pk, (short4_t*)(ob + frag * 256 + lane * 4));
                }
        }
        bar_lgkm();   // bar C: LDS reads done; O NT-stores NOT drained (overlap next P0)
    }
}

// ================================================================
// Kernel B v3 (unchanged from R12): two-pass K-split out-projection.
// ================================================================
#define OPJ_STRIDE 520
__global__ __launch_bounds__(512, 4) void out_proj(
        const unsigned short* __restrict__ O_p,
        const unsigned short* __restrict__ pw,    // packed [24 nt][32 kt][64][8]
        const float* __restrict__ pb,
        float* __restrict__ out) {

    __shared__ unsigned short osB[64 * OPJ_STRIDE];   // 66,560 B

    const int tid  = threadIdx.x;
    const int lane = tid & 63;
    const int wid  = tid >> 6;       // 0..7 -> c-triple
    const int l15  = lane & 15;
    const int lg   = lane >> 4;
    const int b    = blockIdx.x;

    const short8* pwp = (const short8*)pw;
    f32x4 acc[3][4];
#pragma unroll
    for (int i = 0; i < 3; ++i)
#pragma unroll
        for (int I = 0; I < 4; ++I) acc[i][I] = (f32x4)0.f;

#pragma unroll
    for (int p = 0; p < 2; ++p) {
        const short8* obase = (const short8*)(O_p + (size_t)b * 65536 + p * 32768);
        short8 vv[8];
#pragma unroll
        for (int it = 0; it < 8; ++it)
            vv[it] = __builtin_nontemporal_load(obase + tid + it * 512);
        if (p) __syncthreads();            // pass-0 k-loop reads done before overwrite
#pragma unroll
        for (int it = 0; it < 8; ++it) {
            int s = tid + it * 512;
            int fl0 = s * 2;
            int hl   = fl0 >> 11;
            int frag = (fl0 >> 6) & 31;
            int ln0  = fl0 & 63;
            int mt = frag >> 3, dt = frag & 7;
            short8 v = vv[it];
#pragma unroll
            for (int q = 0; q < 2; ++q) {
                int ln = ln0 + q;
                int n0 = mt * 16 + ((ln >> 4) << 2);
                int d  = hl * 128 + dt * 16 + (ln & 15);
#pragma unroll
                for (int r = 0; r < 4; ++r)
                    osB[(n0 + r) * OPJ_STRIDE + d] = (unsigned short)v[q * 4 + r];
            }
        }
        __syncthreads();

        for (int ktl = 0; ktl < 16; ++ktl) {
            short8 bfr[4];
#pragma unroll
            for (int I = 0; I < 4; ++I)
                bfr[I] = *(const short8*)&osB[(I * 16 + l15) * OPJ_STRIDE + ktl * 32 + lg * 8];
#pragma unroll
            for (int i = 0; i < 3; ++i) {
                short8 a = pwp[((size_t)(wid * 3 + i) * 32 + p * 16 + ktl) * 64 + lane];
#pragma unroll
                for (int I = 0; I < 4; ++I) acc[i][I] = MFMA(a, bfr[I], acc[i][I]);
            }
        }
    }

    float* obaseo = out + (size_t)b * (NTOK * 384);
#pragma unroll
    for (int i = 0; i < 3; ++i) {
        int c0 = (wid * 3 + i) * 16 + lg * 4;
        f32x4 bias4 = *(const f32x4*)&pb[c0];
#pragma unroll
        for (int I = 0; I < 4; ++I) {
            int n = I * 16 + l15;
            if (n < 49) {
                f32x4 v = acc[i][I] + bias4;
                __builtin_nontemporal_store(v, (f32x4*)&obaseo[n * 384 + c0]);
            }
        }
    }
}

// ================================================================
// FALLBACK: R4 fused kernel (used if ws too small for O intermediate)
// ================================================================
__global__ __launch_bounds__(512) void fused_attn(
        const float* __restrict__ x,
        const unsigned short* __restrict__ qkw,
        const unsigned short* __restrict__ vw,
        const unsigned short* __restrict__ pw,
        const float* __restrict__ qb_s, const float* __restrict__ kb,
        const float* __restrict__ vb, const float* __restrict__ pb,
        const float* __restrict__ ab_t,
        float* __restrict__ out) {

    __shared__ __align__(16) unsigned short smem[40656];
    unsigned short* xs  = smem;
    unsigned short* ps  = smem + 19208;
    unsigned short* vsT = smem + 22736;
    unsigned short* qs  = smem + 31952;
    unsigned short* ks2 = smem + 31952 + 2560;
    unsigned short* osA = smem + 31952;

    const int tid  = threadIdx.x;
    const int lane = tid & 63;
    const int wid  = tid >> 6;
    const int l15  = lane & 15;
    const int lg   = lane >> 4;
    const int b    = blockIdx.x;

    const float* xb = x + (size_t)b * (NTOK * DIM);
#pragma unroll 2
    for (int i = tid; i < 4704; i += 512) {
        f32x4 v = __builtin_nontemporal_load(((const f32x4*)xb) + i);
        int f = i * 4;
        int row = f / DIM;
        int col = f - row * DIM;
        short4_t pk;
        pk[0] = (short)f2bf(v[0]); pk[1] = (short)f2bf(v[1]);
        pk[2] = (short)f2bf(v[2]); pk[3] = (short)f2bf(v[3]);
        *(short4_t*)&xs[row * 392 + col] = pk;
    }
    __syncthreads();

    f32x4 pacc[3][4];
#pragma unroll
    for (int i = 0; i < 3; ++i)
#pragma unroll
        for (int j = 0; j < 4; ++j) pacc[i][j] = (f32x4)0.f;

    const f32x4 zf = (f32x4)0.f;

    for (int h = 0; h < HEADS; ++h) {
        {
            const int mh  = wid >> 2;
            const int nt0 = 3 * (wid & 3);
            const int rA0 = min(mh * 32 + l15, 48);
            const int rA1 = min(mh * 32 + 16 + l15, 48);
            f32x4 acc[3][2];
#pragma unroll
            for (int i = 0; i < 3; ++i) { acc[i][0] = zf; acc[i][1] = zf; }

            const short8* bptr[3];
#pragma unroll
            for (int i = 0; i < 3; ++i) {
                int nt = nt0 + i;
                const unsigned short* base; int ntile;
                if (nt < 2)      { base = qkw; ntile = 2 * h + nt; }
                else if (nt < 4) { base = qkw; ntile = 16 + 2 * h + (nt - 2); }
                else             { base = vw;  ntile = 8 * h + (nt - 4); }
                bptr[i] = (const short8*)(base + (size_t)ntile * 12 * 64 * 8);
            }
#pragma unroll
            for (int kt = 0; kt < 12; ++kt) {
                short8 a0 = *(const short8*)&xs[rA0 * 392 + kt * 32 + lg * 8];
                short8 a1 = *(const short8*)&xs[rA1 * 392 + kt * 32 + lg * 8];
#pragma unroll
                for (int i = 0; i < 3; ++i) {
                    short8 bf = bptr[i][kt * 64 + lane];
                    acc[i][0] = MFMA(a0, bf, acc[i][0]);
                    acc[i][1] = MFMA(a1, bf, acc[i][1]);
                }
            }
#pragma unroll
            for (int i = 0; i < 3; ++i) {
                int nt = nt0 + i;
                int c  = nt * 16 + l15;
                if (nt < 4) {
                    int cc = (nt < 2) ? c : c - 32;
                    float bias = (nt < 2) ? qb_s[h * 32 + cc] : kb[h * 32 + cc];
                    unsigned short* dst = (nt < 2) ? qs : ks2;
#pragma unroll
                    for (int j = 0; j < 2; ++j) {
                        int r0 = mh * 32 + j * 16 + lg * 4;
                        f32x4 v = acc[i][j];
#pragma unroll
                        for (int r = 0; r < 4; ++r)
                            dst[(r0 + r) * 40 + cc] = f2bf(v[r] + bias);
                    }
                } else {
                    int d = c - 64;
                    float bias = vb[h * 128 + d];
#pragma unroll
                    for (int j = 0; j < 2; ++j) {
                        int m0 = mh * 32 + j * 16 + lg * 4;
                        f32x4 v = acc[i][j];
                        short4_t pk;
#pragma unroll
                        for (int r = 0; r < 4; ++r) pk[r] = (short)f2bf(v[r] + bias);
                        *(short4_t*)&vsT[d * 72 + m0] = pk;
                    }
                }
            }
        }
        __syncthreads();

        if (wid < 4) {
            const int I = wid;
            const int rq = min(I * 16 + l15, 48);
            short8 bq = *(const short8*)&qs[rq * 40 + lg * 8];
            f32x4 s[4];
#pragma unroll
            for (int J = 0; J < 4; ++J) {
                short8 ak = *(const short8*)&ks2[(J * 16 + l15) * 40 + lg * 8];
                s[J] = MFMA(ak, bq, zf);
            }
            const f32x4* abn = (const f32x4*)(ab_t + ((h * 64 + I * 16 + l15) * 64));
            float sv[16];
            float mx = -1e30f;
#pragma unroll
            for (int J = 0; J < 4; ++J) {
                f32x4 a4 = abn[J * 4 + lg];
#pragma unroll
                for (int r = 0; r < 4; ++r) {
                    int m = J * 16 + lg * 4 + r;
                    float val = s[J][r] + a4[r];
                    if (m >= 49) val = -1e30f;
                    sv[J * 4 + r] = val;
                    mx = fmaxf(mx, val);
                }
            }
            mx = fmaxf(mx, __shfl_xor(mx, 16));
            mx = fmaxf(mx, __shfl_xor(mx, 32));
            float sum = 0.f;
#pragma unroll
            for (int t = 0; t < 16; ++t) { float e = __expf(sv[t] - mx); sv[t] = e; sum += e; }
            sum += __shfl_xor(sum, 16);
            sum += __shfl_xor(sum, 32);
            float inv = 1.0f / sum;
            int n = I * 16 + l15;
            if (n < 49) {
#pragma unroll
                for (int J = 0; J < 4; ++J)
#pragma unroll
                    for (int r = 0; r < 4; ++r) {
                        int m = J * 16 + lg * 4 + r;
                        ps[n * 72 + m] = f2bf(sv[J * 4 + r] * inv);
                    }
            }
        }
        __syncthreads();

        {
            const int np = wid >> 2;
            const int dp = wid & 3;
            const int rp0 = min(np * 32 + l15, 48);
            const int rp1 = min(np * 32 + 16 + l15, 48);
            f32x4 a00 = zf, a01 = zf, a10 = zf, a11 = zf;
#pragma unroll
            for (int kk = 0; kk < 2; ++kk) {
                short8 a0 = *(const short8*)&ps[rp0 * 72 + kk * 32 + lg * 8];
                short8 a1 = *(const short8*)&ps[rp1 * 72 + kk * 32 + lg * 8];
                short8 b0 = *(const short8*)&vsT[(dp * 32 + l15) * 72 + kk * 32 + lg * 8];
                short8 b1 = *(const short8*)&vsT[(dp * 32 + 16 + l15) * 72 + kk * 32 + lg * 8];
                a00 = MFMA(a0, b0, a00); a01 = MFMA(a0, b1, a01);
                a10 = MFMA(a1, b0, a10); a11 = MFMA(a1, b1, a11);
            }
            f32x4 accs[2][2] = {{a00, a01}, {a10, a11}};
#pragma unroll
            for (int jn = 0; jn < 2; ++jn)
#pragma unroll
                for (int jd = 0; jd < 2; ++jd) {
                    int r0 = np * 32 + jn * 16 + lg * 4;
                    int d0 = dp * 32 + jd * 16 + l15;
                    f32x4 v = accs[jn][jd];
#pragma unroll
                    for (int r = 0; r < 4; ++r) osA[(r0 + r) * 136 + d0] = f2bf(v[r]);
                }
        }
        __syncthreads();

        {
            const int nt0 = 3 * wid;
#pragma unroll
            for (int kt = 0; kt < 4; ++kt) {
                short8 a[4];
#pragma unroll
                for (int mi = 0; mi < 4; ++mi)
                    a[mi] = *(const short8*)&osA[(mi * 16 + l15) * 136 + kt * 32 + lg * 8];
#pragma unroll
                for (int i = 0; i < 3; ++i) {
                    short8 bf = ((const short8*)pw)[((size_t)(nt0 + i) * 32 + (h * 4 + kt)) * 64 + lane];
#pragma unroll
                    for (int mi = 0; mi < 4; ++mi)
                        pacc[i][mi] = MFMA(a[mi], bf, pacc[i][mi]);
                }
            }
        }
        __syncthreads();
    }

    float* ob = out + (size_t)b * (NTOK * 384);
#pragma unroll
    for (int i = 0; i < 3; ++i) {
        int c = (3 * wid + i) * 16 + l15;
        float bias = pb[c];
#pragma unroll
        for (int mi = 0; mi < 4; ++mi) {
            f32x4 v = pacc[i][mi];
#pragma unroll
            for (int r = 0; r < 4; ++r) {
                int n = mi * 16 + lg * 4 + r;
                if (n < 49) __builtin_nontemporal_store(v[r] + bias, &ob[n * 384 + c]);
            }
        }
    }
}

extern "C" void kernel_launch(void* const* d_in, const int* in_sizes, int n_in,
                              void* d_out, int out_size, void* d_ws, size_t ws_size,
                              hipStream_t stream) {
    const float* x      = (const float*)d_in[0];
    const float* qw     = (const float*)d_in[1];
    const float* qb     = (const float*)d_in[2];
    const float* kw     = (const float*)d_in[3];
    const float* kb     = (const float*)d_in[4];
    const float* vw     = (const float*)d_in[5];
    const float* vb     = (const float*)d_in[6];
    const float* pw     = (const float*)d_in[7];
    const float* pb     = (const float*)d_in[8];
    const float* biases = (const float*)d_in[9];
    const int*   idxs   = (const int*)d_in[10];
    int n_off = in_sizes[9] / HEADS;

    char* ws = (char*)d_ws;
    unsigned short* qk_p = (unsigned short*)ws;                    // 393,216 B
    unsigned short* vw_p = (unsigned short*)(ws + 393216);         // 786,432 B
    unsigned short* pw_p = (unsigned short*)(ws + 1179648);        // 786,432 B
    float*          qb_s = (float*)(ws + 1966080);                 //   1,024 B
    float*          ab_t = (float*)(ws + 1967104);                 // 131,072 B
    unsigned short* O_p  = (unsigned short*)(ws + 2098176);        // 268,435,456 B

    const size_t need = 2098176ull + (size_t)2048 * 8 * 32 * 256 * 2;

    prologue<<<609, 256, 0, stream>>>(qw, qb, kw, vw, pw, biases, idxs, n_off,
                                      qk_p, vw_p, pw_p, qb_s, ab_t);
    if (ws_size >= need) {
        attn_qkv<<<2048, 512, 0, stream>>>(x, qk_p, vw_p, qb_s, kb, vb, ab_t, O_p);
        out_proj<<<2048, 512, 0, stream>>>(O_p, pw_p, pb, (float*)d_out);
    } else {
        fused_attn<<<2048, 512, 0, stream>>>(x, qk_p, vw_p, pw_p, qb_s, kb, vb, pb,
                                             ab_t, (float*)d_out);
    }
}

// Round 15
// 413.683 us; speedup vs baseline: 1.0554x; 1.0554x over previous
//
#include <hip/hip_runtime.h>
#include <hip/hip_bf16.h>

#define NTOK   49
#define DIM    384
#define KEY_DIM 32
#define HEADS  8
#define D_HEAD 128
#define SCALE  0.17677669529663687f   // 32^-0.5

typedef short short8 __attribute__((ext_vector_type(8)));
typedef short short4_t __attribute__((ext_vector_type(4)));
typedef float f32x4 __attribute__((ext_vector_type(4)));

__device__ __forceinline__ unsigned short f2bf(float x) {
    union { __hip_bfloat16 b; unsigned short u; } v;
    v.b = __float2bfloat16(x);            // native HW cvt (RNE)
    return v.u;
}

__device__ __forceinline__ f32x4 MFMA(short8 a, short8 b, f32x4 c) {
    return __builtin_amdgcn_mfma_f32_16x16x32_bf16(a, b, c, 0, 0, 0);
}

// Barrier that drains ONLY LDS ops (lgkmcnt), not in-flight global loads /
// NT stores (vmcnt). Valid when all cross-wave hazards are LDS-resident.
__device__ __forceinline__ void bar_lgkm() {
    asm volatile("s_waitcnt lgkmcnt(0)" ::: "memory");
    __builtin_amdgcn_sched_barrier(0);
    __builtin_amdgcn_s_barrier();
    __builtin_amdgcn_sched_barrier(0);
}

// ---------------- prologue: weight packing + bias expansion ----------------
__global__ void prologue(const float* __restrict__ qw, const float* __restrict__ qb,
                         const float* __restrict__ kw,
                         const float* __restrict__ vw, const float* __restrict__ pw,
                         const float* __restrict__ biases, const int* __restrict__ idxs,
                         int n_off,
                         unsigned short* __restrict__ qk_p,
                         unsigned short* __restrict__ vw_p,
                         unsigned short* __restrict__ pw_p,
                         float* __restrict__ qb_s,
                         float* __restrict__ ab_t) {
    int t = blockIdx.x * 256 + threadIdx.x;
    if (t < 24576) {                       // QK pack: N=512 (Q|K), K=384, KT=12
        int lane = t & 63, kt = (t >> 6) % 12, ntile = t / 768;
        int c = ntile * 16 + (lane & 15), kk = kt * 32 + (lane >> 4) * 8;
        const float* src = (c < 256) ? (qw + c * 384 + kk) : (kw + (c - 256) * 384 + kk);
        float sc = (c < 256) ? SCALE : 1.0f;
        short8 o;
#pragma unroll
        for (int j = 0; j < 8; ++j) o[j] = (short)f2bf(src[j] * sc);
        *(short8*)(qk_p + (size_t)t * 8) = o;
    } else if (t < 73728) {                // V pack: N=1024, K=384, KT=12
        int u = t - 24576;
        int lane = u & 63, kt = (u >> 6) % 12, ntile = u / 768;
        int c = ntile * 16 + (lane & 15), kk = kt * 32 + (lane >> 4) * 8;
        const float* src = vw + c * 384 + kk;
        short8 o;
#pragma unroll
        for (int j = 0; j < 8; ++j) o[j] = (short)f2bf(src[j]);
        *(short8*)(vw_p + (size_t)u * 8) = o;
    } else if (t < 122880) {               // proj pack: N=384, K=1024, KT=32
        int u = t - 73728;
        int lane = u & 63, kt = (u >> 6) % 32, ntile = u / 2048;
        int c = ntile * 16 + (lane & 15), kk = kt * 32 + (lane >> 4) * 8;
        const float* src = pw + c * 1024 + kk;
        short8 o;
#pragma unroll
        for (int j = 0; j < 8; ++j) o[j] = (short)f2bf(src[j]);
        *(short8*)(pw_p + (size_t)u * 8) = o;
    } else if (t < 123136) {               // scaled q bias
        int u = t - 122880;
        qb_s[u] = qb[u] * SCALE;
    } else if (t < 123136 + 32768) {       // ab_t[h][n][m] (n=query, m=key), zero-padded 64x64
        int u = t - 123136;
        int h = u >> 12, n = (u >> 6) & 63, m = u & 63;
        float v = 0.f;
        if (m < 49 && n < 49) v = biases[h * n_off + idxs[n * 49 + m]];
        ab_t[u] = v;
    }
}

// ================================================================
// Kernel A (R12 / best-measured): QKV proj + attention + PV -> O C-frag.
//   O_p ushort offset (((b*8+h)*32 + frag)*64 + ln)*4 + r  holds
//   O[b][n = mt*16 + (ln>>4)*4 + r][dglob = h*128 + dt*16 + (ln&15)],
//   frag = mt*8 + dt.
// 8 heads/block, grid 2048. LDS 74,144 B -> 2 blocks/CU, (512,4).
// NOTE (measured): do NOT manually double-buffer P0's B-frags (R14: -8%)
// and do NOT role-split waves across phases (R13: -5%) — the compiler
// schedule + 2-block TLP already cover those latencies.
// ================================================================
__global__ __launch_bounds__(512, 4) void attn_qkv(
        const float* __restrict__ x,
        const unsigned short* __restrict__ qkw,
        const unsigned short* __restrict__ vw,
        const float* __restrict__ qb_s, const float* __restrict__ kb,
        const float* __restrict__ vb,
        const float* __restrict__ ab_t,
        unsigned short* __restrict__ O_p) {

    __shared__ __align__(16) unsigned short smem[37072];   // 74,144 B
    unsigned short* xs  = smem;                // [49][392]
    unsigned short* ps  = smem + 19208;        // [49][72]
    unsigned short* vsT = smem + 22736;        // [128][72]
    unsigned short* qs  = smem + 31952;        // [64][40]
    unsigned short* ks2 = smem + 34512;        // [64][40]

    const int tid  = threadIdx.x;
    const int lane = tid & 63;
    const int wid  = tid >> 6;
    const int l15  = lane & 15;
    const int lg   = lane >> 4;
    const int b    = blockIdx.x;

    const float* xb = x + (size_t)b * (NTOK * DIM);
#pragma unroll 2
    for (int i = tid; i < 4704; i += 512) {
        f32x4 v = __builtin_nontemporal_load(((const f32x4*)xb) + i);
        int f = i * 4;
        int row = f / DIM;
        int col = f - row * DIM;
        short4_t pk;
        pk[0] = (short)f2bf(v[0]); pk[1] = (short)f2bf(v[1]);
        pk[2] = (short)f2bf(v[2]); pk[3] = (short)f2bf(v[3]);
        *(short4_t*)&xs[row * 392 + col] = pk;
    }
    __syncthreads();   // full drain once (staging)

    const f32x4 zf = (f32x4)0.f;

    for (int h = 0; h < HEADS; ++h) {
        // ---- P0: Q,K,V projection ----
        {
            const int mh  = wid >> 2;
            const int nt0 = 3 * (wid & 3);
            const int rA0 = min(mh * 32 + l15, 48);
            const int rA1 = min(mh * 32 + 16 + l15, 48);
            f32x4 acc[3][2];
#pragma unroll
            for (int i = 0; i < 3; ++i) { acc[i][0] = zf; acc[i][1] = zf; }

            const short8* bptr[3];
#pragma unroll
            for (int i = 0; i < 3; ++i) {
                int nt = nt0 + i;
                const unsigned short* base; int ntile;
                if (nt < 2)      { base = qkw; ntile = 2 * h + nt; }
                else if (nt < 4) { base = qkw; ntile = 16 + 2 * h + (nt - 2); }
                else             { base = vw;  ntile = 8 * h + (nt - 4); }
                bptr[i] = (const short8*)(base + (size_t)ntile * 12 * 64 * 8);
            }
            __builtin_amdgcn_s_setprio(1);
#pragma unroll
            for (int kt = 0; kt < 12; ++kt) {
                short8 a0 = *(const short8*)&xs[rA0 * 392 + kt * 32 + lg * 8];
                short8 a1 = *(const short8*)&xs[rA1 * 392 + kt * 32 + lg * 8];
#pragma unroll
                for (int i = 0; i < 3; ++i) {
                    short8 bf = bptr[i][kt * 64 + lane];
                    acc[i][0] = MFMA(a0, bf, acc[i][0]);
                    acc[i][1] = MFMA(a1, bf, acc[i][1]);
                }
            }
            __builtin_amdgcn_s_setprio(0);
#pragma unroll
            for (int i = 0; i < 3; ++i) {
                int nt = nt0 + i;
                int c  = nt * 16 + l15;
                if (nt < 4) {
                    int cc = (nt < 2) ? c : c - 32;
                    float bias = (nt < 2) ? qb_s[h * 32 + cc] : kb[h * 32 + cc];
                    unsigned short* dst = (nt < 2) ? qs : ks2;
#pragma unroll
                    for (int j = 0; j < 2; ++j) {
                        int r0 = mh * 32 + j * 16 + lg * 4;
                        f32x4 v = acc[i][j];
#pragma unroll
                        for (int r = 0; r < 4; ++r)
                            dst[(r0 + r) * 40 + cc] = f2bf(v[r] + bias);
                    }
                } else {
                    int d = c - 64;
                    float bias = vb[h * 128 + d];
#pragma unroll
                    for (int j = 0; j < 2; ++j) {
                        int m0 = mh * 32 + j * 16 + lg * 4;
                        f32x4 v = acc[i][j];
                        short4_t pk;
#pragma unroll
                        for (int r = 0; r < 4; ++r) pk[r] = (short)f2bf(v[r] + bias);
                        *(short4_t*)&vsT[d * 72 + m0] = pk;
                    }
                }
            }
        }
        bar_lgkm();   // bar A: qs/ks/vsT ready (LDS only)

        // ---- P1: S^T = K@Q^T, softmax (waves 0-3) ----
        if (wid < 4) {
            const int I = wid;
            const int rq = min(I * 16 + l15, 48);
            short8 bq = *(const short8*)&qs[rq * 40 + lg * 8];
            f32x4 s[4];
#pragma unroll
            for (int J = 0; J < 4; ++J) {
                short8 ak = *(const short8*)&ks2[(J * 16 + l15) * 40 + lg * 8];
                s[J] = MFMA(ak, bq, zf);
            }
            const f32x4* abn = (const f32x4*)(ab_t + ((h * 64 + I * 16 + l15) * 64));
            float sv[16];
            float mx = -1e30f;
#pragma unroll
            for (int J = 0; J < 4; ++J) {
                f32x4 a4 = abn[J * 4 + lg];
#pragma unroll
                for (int r = 0; r < 4; ++r) {
                    int m = J * 16 + lg * 4 + r;
                    float val = s[J][r] + a4[r];
                    if (m >= 49) val = -1e30f;
                    sv[J * 4 + r] = val;
                    mx = fmaxf(mx, val);
                }
            }
            mx = fmaxf(mx, __shfl_xor(mx, 16));
            mx = fmaxf(mx, __shfl_xor(mx, 32));
            float sum = 0.f;
#pragma unroll
            for (int t = 0; t < 16; ++t) { float e = __expf(sv[t] - mx); sv[t] = e; sum += e; }
            sum += __shfl_xor(sum, 16);
            sum += __shfl_xor(sum, 32);
            float inv = 1.0f / sum;
            int n = I * 16 + l15;
            if (n < 49) {
#pragma unroll
                for (int J = 0; J < 4; ++J)
#pragma unroll
                    for (int r = 0; r < 4; ++r) {
                        int m = J * 16 + lg * 4 + r;
                        ps[n * 72 + m] = f2bf(sv[J * 4 + r] * inv);
                    }
            }
        }
        bar_lgkm();   // bar B: ps ready (LDS only)

        // ---- P2a: O_h = P @ V_h -> direct packed global store (C-frag) ----
        {
            const int np = wid >> 2;
            const int dp = wid & 3;
            const int rp0 = min(np * 32 + l15, 48);
            const int rp1 = min(np * 32 + 16 + l15, 48);
            f32x4 a00 = zf, a01 = zf, a10 = zf, a11 = zf;
            __builtin_amdgcn_s_setprio(1);
#pragma unroll
            for (int kk = 0; kk < 2; ++kk) {
                short8 a0 = *(const short8*)&ps[rp0 * 72 + kk * 32 + lg * 8];
                short8 a1 = *(const short8*)&ps[rp1 * 72 + kk * 32 + lg * 8];
                short8 b0 = *(const short8*)&vsT[(dp * 32 + l15) * 72 + kk * 32 + lg * 8];
                short8 b1 = *(const short8*)&vsT[(dp * 32 + 16 + l15) * 72 + kk * 32 + lg * 8];
                a00 = MFMA(a0, b0, a00); a01 = MFMA(a0, b1, a01);
                a10 = MFMA(a1, b0, a10); a11 = MFMA(a1, b1, a11);
            }
            __builtin_amdgcn_s_setprio(0);
            f32x4 accs[2][2] = {{a00, a01}, {a10, a11}};
            unsigned short* ob = O_p + (((size_t)b * 8 + h) * 32) * 256;
#pragma unroll
            for (int jn = 0; jn < 2; ++jn)
#pragma unroll
                for (int jd = 0; jd < 2; ++jd) {
                    int frag = (np * 2 + jn) * 8 + (dp * 2 + jd);
                    f32x4 v = accs[jn][jd];
                    short4_t pk;
#pragma unroll
                    for (int r = 0; r < 4; ++r) pk[r] = (short)f2bf(v[r]);
                    __builtin_nontemporal_store(pk, (short4_t*)(ob + frag * 256 + lane * 4));
                }
        }
        bar_lgkm();   // bar C: LDS reads done; O NT-stores NOT drained (overlap next P0)
    }
}

// ================================================================
// Kernel B v3 (R12): two-pass K-split out-projection.
// Pass p: restage heads 4p..4p+3 into osB[64][520] (66,560 B ->
// 2 blocks/CU), k-loop kt = 16p..16p+15; acc[3][4] persists.
// ================================================================
#define OPJ_STRIDE 520
__global__ __launch_bounds__(512, 4) void out_proj(
        const unsigned short* __restrict__ O_p,
        const unsigned short* __restrict__ pw,    // packed [24 nt][32 kt][64][8]
        const float* __restrict__ pb,
        float* __restrict__ out) {

    __shared__ unsigned short osB[64 * OPJ_STRIDE];   // 66,560 B

    const int tid  = threadIdx.x;
    const int lane = tid & 63;
    const int wid  = tid >> 6;       // 0..7 -> c-triple
    const int l15  = lane & 15;
    const int lg   = lane >> 4;
    const int b    = blockIdx.x;

    const short8* pwp = (const short8*)pw;
    f32x4 acc[3][4];
#pragma unroll
    for (int i = 0; i < 3; ++i)
#pragma unroll
        for (int I = 0; I < 4; ++I) acc[i][I] = (f32x4)0.f;

#pragma unroll
    for (int p = 0; p < 2; ++p) {
        const short8* obase = (const short8*)(O_p + (size_t)b * 65536 + p * 32768);
        short8 vv[8];
#pragma unroll
        for (int it = 0; it < 8; ++it)
            vv[it] = __builtin_nontemporal_load(obase + tid + it * 512);
        if (p) __syncthreads();            // pass-0 k-loop reads done before overwrite
#pragma unroll
        for (int it = 0; it < 8; ++it) {
            int s = tid + it * 512;
            int fl0 = s * 2;
            int hl   = fl0 >> 11;
            int frag = (fl0 >> 6) & 31;
            int ln0  = fl0 & 63;
            int mt = frag >> 3, dt = frag & 7;
            short8 v = vv[it];
#pragma unroll
            for (int q = 0; q < 2; ++q) {
                int ln = ln0 + q;
                int n0 = mt * 16 + ((ln >> 4) << 2);
                int d  = hl * 128 + dt * 16 + (ln & 15);
#pragma unroll
                for (int r = 0; r < 4; ++r)
                    osB[(n0 + r) * OPJ_STRIDE + d] = (unsigned short)v[q * 4 + r];
            }
        }
        __syncthreads();

        for (int ktl = 0; ktl < 16; ++ktl) {
            short8 bfr[4];
#pragma unroll
            for (int I = 0; I < 4; ++I)
                bfr[I] = *(const short8*)&osB[(I * 16 + l15) * OPJ_STRIDE + ktl * 32 + lg * 8];
#pragma unroll
            for (int i = 0; i < 3; ++i) {
                short8 a = pwp[((size_t)(wid * 3 + i) * 32 + p * 16 + ktl) * 64 + lane];
#pragma unroll
                for (int I = 0; I < 4; ++I) acc[i][I] = MFMA(a, bfr[I], acc[i][I]);
            }
        }
    }

    float* obaseo = out + (size_t)b * (NTOK * 384);
#pragma unroll
    for (int i = 0; i < 3; ++i) {
        int c0 = (wid * 3 + i) * 16 + lg * 4;
        f32x4 bias4 = *(const f32x4*)&pb[c0];
#pragma unroll
        for (int I = 0; I < 4; ++I) {
            int n = I * 16 + l15;
            if (n < 49) {
                f32x4 v = acc[i][I] + bias4;
                __builtin_nontemporal_store(v, (f32x4*)&obaseo[n * 384 + c0]);
            }
        }
    }
}

// ================================================================
// FALLBACK: R4 fused kernel (used if ws too small for O intermediate)
// ================================================================
__global__ __launch_bounds__(512) void fused_attn(
        const float* __restrict__ x,
        const unsigned short* __restrict__ qkw,
        const unsigned short* __restrict__ vw,
        const unsigned short* __restrict__ pw,
        const float* __restrict__ qb_s, const float* __restrict__ kb,
        const float* __restrict__ vb, const float* __restrict__ pb,
        const float* __restrict__ ab_t,
        float* __restrict__ out) {

    __shared__ __align__(16) unsigned short smem[40656];
    unsigned short* xs  = smem;
    unsigned short* ps  = smem + 19208;
    unsigned short* vsT = smem + 22736;
    unsigned short* qs  = smem + 31952;
    unsigned short* ks2 = smem + 31952 + 2560;
    unsigned short* osA = smem + 31952;

    const int tid  = threadIdx.x;
    const int lane = tid & 63;
    const int wid  = tid >> 6;
    const int l15  = lane & 15;
    const int lg   = lane >> 4;
    const int b    = blockIdx.x;

    const float* xb = x + (size_t)b * (NTOK * DIM);
#pragma unroll 2
    for (int i = tid; i < 4704; i += 512) {
        f32x4 v = __builtin_nontemporal_load(((const f32x4*)xb) + i);
        int f = i * 4;
        int row = f / DIM;
        int col = f - row * DIM;
        short4_t pk;
        pk[0] = (short)f2bf(v[0]); pk[1] = (short)f2bf(v[1]);
        pk[2] = (short)f2bf(v[2]); pk[3] = (short)f2bf(v[3]);
        *(short4_t*)&xs[row * 392 + col] = pk;
    }
    __syncthreads();

    f32x4 pacc[3][4];
#pragma unroll
    for (int i = 0; i < 3; ++i)
#pragma unroll
        for (int j = 0; j < 4; ++j) pacc[i][j] = (f32x4)0.f;

    const f32x4 zf = (f32x4)0.f;

    for (int h = 0; h < HEADS; ++h) {
        {
            const int mh  = wid >> 2;
            const int nt0 = 3 * (wid & 3);
            const int rA0 = min(mh * 32 + l15, 48);
            const int rA1 = min(mh * 32 + 16 + l15, 48);
            f32x4 acc[3][2];
#pragma unroll
            for (int i = 0; i < 3; ++i) { acc[i][0] = zf; acc[i][1] = zf; }

            const short8* bptr[3];
#pragma unroll
            for (int i = 0; i < 3; ++i) {
                int nt = nt0 + i;
                const unsigned short* base; int ntile;
                if (nt < 2)      { base = qkw; ntile = 2 * h + nt; }
                else if (nt < 4) { base = qkw; ntile = 16 + 2 * h + (nt - 2); }
                else             { base = vw;  ntile = 8 * h + (nt - 4); }
                bptr[i] = (const short8*)(base + (size_t)ntile * 12 * 64 * 8);
            }
#pragma unroll
            for (int kt = 0; kt < 12; ++kt) {
                short8 a0 = *(const short8*)&xs[rA0 * 392 + kt * 32 + lg * 8];
                short8 a1 = *(const short8*)&xs[rA1 * 392 + kt * 32 + lg * 8];
#pragma unroll
                for (int i = 0; i < 3; ++i) {
                    short8 bf = bptr[i][kt * 64 + lane];
                    acc[i][0] = MFMA(a0, bf, acc[i][0]);
                    acc[i][1] = MFMA(a1, bf, acc[i][1]);
                }
            }
#pragma unroll
            for (int i = 0; i < 3; ++i) {
                int nt = nt0 + i;
                int c  = nt * 16 + l15;
                if (nt < 4) {
                    int cc = (nt < 2) ? c : c - 32;
                    float bias = (nt < 2) ? qb_s[h * 32 + cc] : kb[h * 32 + cc];
                    unsigned short* dst = (nt < 2) ? qs : ks2;
#pragma unroll
                    for (int j = 0; j < 2; ++j) {
                        int r0 = mh * 32 + j * 16 + lg * 4;
                        f32x4 v = acc[i][j];
#pragma unroll
                        for (int r = 0; r < 4; ++r)
                            dst[(r0 + r) * 40 + cc] = f2bf(v[r] + bias);
                    }
                } else {
                    int d = c - 64;
                    float bias = vb[h * 128 + d];
#pragma unroll
                    for (int j = 0; j < 2; ++j) {
                        int m0 = mh * 32 + j * 16 + lg * 4;
                        f32x4 v = acc[i][j];
                        short4_t pk;
#pragma unroll
                        for (int r = 0; r < 4; ++r) pk[r] = (short)f2bf(v[r] + bias);
                        *(short4_t*)&vsT[d * 72 + m0] = pk;
                    }
                }
            }
        }
        __syncthreads();

        if (wid < 4) {
            const int I = wid;
            const int rq = min(I * 16 + l15, 48);
            short8 bq = *(const short8*)&qs[rq * 40 + lg * 8];
            f32x4 s[4];
#pragma unroll
            for (int J = 0; J < 4; ++J) {
                short8 ak = *(const short8*)&ks2[(J * 16 + l15) * 40 + lg * 8];
                s[J] = MFMA(ak, bq, zf);
            }
            const f32x4* abn = (const f32x4*)(ab_t + ((h * 64 + I * 16 + l15) * 64));
            float sv[16];
            float mx = -1e30f;
#pragma unroll
            for (int J = 0; J < 4; ++J) {
                f32x4 a4 = abn[J * 4 + lg];
#pragma unroll
                for (int r = 0; r < 4; ++r) {
                    int m = J * 16 + lg * 4 + r;
                    float val = s[J][r] + a4[r];
                    if (m >= 49) val = -1e30f;
                    sv[J * 4 + r] = val;
                    mx = fmaxf(mx, val);
                }
            }
            mx = fmaxf(mx, __shfl_xor(mx, 16));
            mx = fmaxf(mx, __shfl_xor(mx, 32));
            float sum = 0.f;
#pragma unroll
            for (int t = 0; t < 16; ++t) { float e = __expf(sv[t] - mx); sv[t] = e; sum += e; }
            sum += __shfl_xor(sum, 16);
            sum += __shfl_xor(sum, 32);
            float inv = 1.0f / sum;
            int n = I * 16 + l15;
            if (n < 49) {
#pragma unroll
                for (int J = 0; J < 4; ++J)
#pragma unroll
                    for (int r = 0; r < 4; ++r) {
                        int m = J * 16 + lg * 4 + r;
                        ps[n * 72 + m] = f2bf(sv[J * 4 + r] * inv);
                    }
            }
        }
        __syncthreads();

        {
            const int np = wid >> 2;
            const int dp = wid & 3;
            const int rp0 = min(np * 32 + l15, 48);
            const int rp1 = min(np * 32 + 16 + l15, 48);
            f32x4 a00 = zf, a01 = zf, a10 = zf, a11 = zf;
#pragma unroll
            for (int kk = 0; kk < 2; ++kk) {
                short8 a0 = *(const short8*)&ps[rp0 * 72 + kk * 32 + lg * 8];
                short8 a1 = *(const short8*)&ps[rp1 * 72 + kk * 32 + lg * 8];
                short8 b0 = *(const short8*)&vsT[(dp * 32 + l15) * 72 + kk * 32 + lg * 8];
                short8 b1 = *(const short8*)&vsT[(dp * 32 + 16 + l15) * 72 + kk * 32 + lg * 8];
                a00 = MFMA(a0, b0, a00); a01 = MFMA(a0, b1, a01);
                a10 = MFMA(a1, b0, a10); a11 = MFMA(a1, b1, a11);
            }
            f32x4 accs[2][2] = {{a00, a01}, {a10, a11}};
#pragma unroll
            for (int jn = 0; jn < 2; ++jn)
#pragma unroll
                for (int jd = 0; jd < 2; ++jd) {
                    int r0 = np * 32 + jn * 16 + lg * 4;
                    int d0 = dp * 32 + jd * 16 + l15;
                    f32x4 v = accs[jn][jd];
#pragma unroll
                    for (int r = 0; r < 4; ++r) osA[(r0 + r) * 136 + d0] = f2bf(v[r]);
                }
        }
        __syncthreads();

        {
            const int nt0 = 3 * wid;
#pragma unroll
            for (int kt = 0; kt < 4; ++kt) {
                short8 a[4];
#pragma unroll
                for (int mi = 0; mi < 4; ++mi)
                    a[mi] = *(const short8*)&osA[(mi * 16 + l15) * 136 + kt * 32 + lg * 8];
#pragma unroll
                for (int i = 0; i < 3; ++i) {
                    short8 bf = ((const short8*)pw)[((size_t)(nt0 + i) * 32 + (h * 4 + kt)) * 64 + lane];
#pragma unroll
                    for (int mi = 0; mi < 4; ++mi)
                        pacc[i][mi] = MFMA(a[mi], bf, pacc[i][mi]);
                }
            }
        }
        __syncthreads();
    }

    float* ob = out + (size_t)b * (NTOK * 384);
#pragma unroll
    for (int i = 0; i < 3; ++i) {
        int c = (3 * wid + i) * 16 + l15;
        float bias = pb[c];
#pragma unroll
        for (int mi = 0; mi < 4; ++mi) {
            f32x4 v = pacc[i][mi];
#pragma unroll
            for (int r = 0; r < 4; ++r) {
                int n = mi * 16 + lg * 4 + r;
                if (n < 49) __builtin_nontemporal_store(v[r] + bias, &ob[n * 384 + c]);
            }
        }
    }
}

extern "C" void kernel_launch(void* const* d_in, const int* in_sizes, int n_in,
                              void* d_out, int out_size, void* d_ws, size_t ws_size,
                              hipStream_t stream) {
    const float* x      = (const float*)d_in[0];
    const float* qw     = (const float*)d_in[1];
    const float* qb     = (const float*)d_in[2];
    const float* kw     = (const float*)d_in[3];
    const float* kb     = (const float*)d_in[4];
    const float* vw     = (const float*)d_in[5];
    const float* vb     = (const float*)d_in[6];
    const float* pw     = (const float*)d_in[7];
    const float* pb     = (const float*)d_in[8];
    const float* biases = (const float*)d_in[9];
    const int*   idxs   = (const int*)d_in[10];
    int n_off = in_sizes[9] / HEADS;

    char* ws = (char*)d_ws;
    unsigned short* qk_p = (unsigned short*)ws;                    // 393,216 B
    unsigned short* vw_p = (unsigned short*)(ws + 393216);         // 786,432 B
    unsigned short* pw_p = (unsigned short*)(ws + 1179648);        // 786,432 B
    float*          qb_s = (float*)(ws + 1966080);                 //   1,024 B
    float*          ab_t = (float*)(ws + 1967104);                 // 131,072 B
    unsigned short* O_p  = (unsigned short*)(ws + 2098176);        // 268,435,456 B

    const size_t need = 2098176ull + (size_t)2048 * 8 * 32 * 256 * 2;

    prologue<<<609, 256, 0, stream>>>(qw, qb, kw, vw, pw, biases, idxs, n_off,
                                      qk_p, vw_p, pw_p, qb_s, ab_t);
    if (ws_size >= need) {
        attn_qkv<<<2048, 512, 0, stream>>>(x, qk_p, vw_p, qb_s, kb, vb, ab_t, O_p);
        out_proj<<<2048, 512, 0, stream>>>(O_p, pw_p, pb, (float*)d_out);
    } else {
        fused_attn<<<2048, 512, 0, stream>>>(x, qk_p, vw_p, pw_p, qb_s, kb, vb, pb,
                                             ab_t, (float*)d_out);
    }
}